// Round 1
// baseline (897.264 us; speedup 1.0000x reference)
//
#include <hip/hip_runtime.h>

// ---------------- problem constants ----------------
constexpr int NB  = 32;     // batch
constexpr int NS  = 1024;   // seq
constexpr int NH  = 768;    // hidden
constexpr int NH2 = 1536;   // 2*hidden
constexpr int NQKV = 2304;  // 3*hidden
constexpr int NBS = NB * NS;

typedef __bf16 bf16x8 __attribute__((ext_vector_type(8)));
typedef float  f32x4  __attribute__((ext_vector_type(4)));
typedef unsigned short u16x8 __attribute__((ext_vector_type(8)));

__device__ __forceinline__ unsigned short f2bf(float f) {
  unsigned int u = __builtin_bit_cast(unsigned int, f);
  u += 0x7FFFu + ((u >> 16) & 1u);
  return (unsigned short)(u >> 16);
}
__device__ __forceinline__ float bf2f(unsigned short h) {
  return __builtin_bit_cast(float, ((unsigned int)h) << 16);
}

#define GLDS16(g, l)                                                         \
  __builtin_amdgcn_global_load_lds(                                          \
      (__attribute__((address_space(1))) void*)(g),                          \
      (__attribute__((address_space(3))) void*)(l), 16, 0, 0)

// ---------------- cond features: per-batch weight/bias ----------------
__launch_bounds__(256)
__global__ void cond_kernel(const int* __restrict__ relation,
                            const float* __restrict__ h,
                            const int* __restrict__ subh,
                            const int* __restrict__ subt,
                            const float* __restrict__ rel_emb,
                            const float* __restrict__ W_rf,
                            const float* __restrict__ b_rf,
                            const float* __restrict__ gamma,
                            const float* __restrict__ beta,
                            const float* __restrict__ W_wd,
                            const float* __restrict__ W_bd,
                            float* __restrict__ wt, float* __restrict__ bs) {
  __shared__ float re[NH], sf[NH], rf[NH];
  const int b = blockIdx.x, t = threadIdx.x;
  const int r = relation[b], sh = subh[b], st = subt[b];
  for (int i = t; i < NH; i += 256) {
    re[i] = rel_emb[(size_t)r * NH + i];
    sf[i] = 0.5f * (h[((size_t)b * NS + sh) * NH + i] +
                    h[((size_t)b * NS + st) * NH + i]);
  }
  __syncthreads();
  for (int j = t; j < NH; j += 256) {
    const float4* w4 = (const float4*)(W_rf + (size_t)j * NH);
    float acc = b_rf[j];
    for (int k = 0; k < NH / 4; k++) {
      float4 wv = w4[k];
      float4 rv = ((const float4*)re)[k];
      acc += wv.x * rv.x + wv.y * rv.y + wv.z * rv.z + wv.w * rv.w;
    }
    rf[j] = fminf(fmaxf(acc, 0.0f), 6.0f);  // ReLU6
  }
  __syncthreads();
  for (int j = t; j < NH; j += 256) {
    const float4* ww = (const float4*)(W_wd + (size_t)j * NH2);
    const float4* wb = (const float4*)(W_bd + (size_t)j * NH2);
    float aw = gamma[j], ab = beta[j];
    for (int k = 0; k < NH / 4; k++) {
      float4 c = ((const float4*)rf)[k];
      float4 a = ww[k], d = wb[k];
      aw += a.x * c.x + a.y * c.y + a.z * c.z + a.w * c.w;
      ab += d.x * c.x + d.y * c.y + d.z * c.z + d.w * c.w;
    }
    for (int k = 0; k < NH / 4; k++) {
      float4 c = ((const float4*)sf)[k];
      float4 a = ww[NH / 4 + k], d = wb[NH / 4 + k];
      aw += a.x * c.x + a.y * c.y + a.z * c.z + a.w * c.w;
      ab += d.x * c.x + d.y * c.y + d.z * c.z + d.w * c.w;
    }
    wt[(size_t)b * NH + j] = aw;
    bs[(size_t)b * NH + j] = ab;
  }
}

// ---------------- conditional layernorm -> x (bf16) ----------------
__launch_bounds__(64)
__global__ void ln_kernel(const float* __restrict__ h,
                          const float* __restrict__ wt,
                          const float* __restrict__ bs,
                          unsigned short* __restrict__ xbf) {
  const int row = blockIdx.x;      // 0..NBS-1
  const int b = row >> 10;
  const int lane = threadIdx.x;    // 0..63
  const float4* hr = (const float4*)(h + (size_t)row * NH);
  float4 v0 = hr[lane], v1 = hr[lane + 64], v2 = hr[lane + 128];
  float sum = 0.f, sq = 0.f;
  {
    sum += v0.x + v0.y + v0.z + v0.w;
    sq  += v0.x * v0.x + v0.y * v0.y + v0.z * v0.z + v0.w * v0.w;
    sum += v1.x + v1.y + v1.z + v1.w;
    sq  += v1.x * v1.x + v1.y * v1.y + v1.z * v1.z + v1.w * v1.w;
    sum += v2.x + v2.y + v2.z + v2.w;
    sq  += v2.x * v2.x + v2.y * v2.y + v2.z * v2.z + v2.w * v2.w;
  }
  for (int off = 32; off > 0; off >>= 1) {
    sum += __shfl_xor(sum, off, 64);
    sq  += __shfl_xor(sq, off, 64);
  }
  const float mean = sum * (1.0f / NH);
  const float var  = sq * (1.0f / NH) - mean * mean;
  const float rstd = rsqrtf(var + 1e-12f);
  const float4* wr = (const float4*)(wt + (size_t)b * NH);
  const float4* br = (const float4*)(bs + (size_t)b * NH);
  ushort4* xr = (ushort4*)(xbf + (size_t)row * NH);
#pragma unroll
  for (int i = 0; i < 3; i++) {
    float4 v = (i == 0) ? v0 : (i == 1) ? v1 : v2;
    float4 w = wr[lane + 64 * i];
    float4 bb = br[lane + 64 * i];
    ushort4 o;
    o.x = f2bf((v.x - mean) * rstd * w.x + bb.x);
    o.y = f2bf((v.y - mean) * rstd * w.y + bb.y);
    o.z = f2bf((v.z - mean) * rstd * w.z + bb.z);
    o.w = f2bf((v.w - mean) * rstd * w.w + bb.w);
    xr[lane + 64 * i] = o;
  }
}

// ---------------- weight prep: Wq/Wk/Wv -> bf16 concat ----------------
__launch_bounds__(256)
__global__ void prep_w(const float* __restrict__ Wq, const float* __restrict__ bq,
                       const float* __restrict__ Wk, const float* __restrict__ bk,
                       const float* __restrict__ Wv, const float* __restrict__ bv,
                       unsigned short* __restrict__ Wcat, float* __restrict__ bcat) {
  const int row = blockIdx.x;  // 0..2303
  const float* Wsrc;
  const float* bsrc;
  int r;
  if (row < NH) { Wsrc = Wq; bsrc = bq; r = row; }
  else if (row < NH2) { Wsrc = Wk; bsrc = bk; r = row - NH; }
  else { Wsrc = Wv; bsrc = bv; r = row - NH2; }
  for (int j = threadIdx.x; j < NH; j += 256)
    Wcat[(size_t)row * NH + j] = f2bf(Wsrc[(size_t)r * NH + j]);
  if (threadIdx.x == 0) bcat[row] = bsrc[r];
}

// ---------------- generic B^T GEMM: C = op(A @ B^T) ----------------
// A: [M,K] bf16 stride lda; B: [N,K] bf16 stride ldb; C: [M,N]
// 128x128 tile, BK=32, 4 waves (2x2), mfma 16x16x32 bf16.
template <int OUT_BF16, int RELU, int HASBIAS, int RES>
__launch_bounds__(256)
__global__ void gemm_bt(const unsigned short* __restrict__ A, long long sAz, int lda,
                        const unsigned short* __restrict__ Bm, long long sBz, int ldb,
                        void* __restrict__ C, long long sCz, int ldc,
                        const float* __restrict__ bias,
                        const unsigned short* __restrict__ Res, long long sRz, int ldr,
                        int K) {
  __shared__ unsigned short lsA[128 * 32];
  __shared__ unsigned short lsB[128 * 32];
  const int t = threadIdx.x;
  const int z = blockIdx.z;
  const int tileN = blockIdx.x * 128;  // N fastest -> B panel L2 reuse
  const int tileM = blockIdx.y * 128;
  const unsigned short* Ab = A + (size_t)z * sAz + (size_t)tileM * lda;
  const unsigned short* Bb = Bm + (size_t)z * sBz + (size_t)tileN * ldb;

  const int lane = t & 63;
  const int w = t >> 6;
  const int wm = w >> 1, wn = w & 1;
  const int lr = lane & 15;
  const int lk = (lane >> 4) << 3;

  f32x4 acc[4][4];
#pragma unroll
  for (int i = 0; i < 4; i++)
#pragma unroll
    for (int j = 0; j < 4; j++) acc[i][j] = (f32x4)0.0f;

  const int rA0 = t >> 2, cA0 = (t & 3) << 3;
  for (int k0 = 0; k0 < K; k0 += 32) {
    GLDS16(Ab + (size_t)rA0 * lda + k0 + cA0, &lsA[t * 8]);
    GLDS16(Ab + (size_t)(rA0 + 64) * lda + k0 + cA0, &lsA[(t + 256) * 8]);
    GLDS16(Bb + (size_t)rA0 * ldb + k0 + cA0, &lsB[t * 8]);
    GLDS16(Bb + (size_t)(rA0 + 64) * ldb + k0 + cA0, &lsB[(t + 256) * 8]);
    __syncthreads();
    bf16x8 aF[4], bF[4];
#pragma unroll
    for (int i = 0; i < 4; i++) {
      aF[i] = *(const bf16x8*)&lsA[(wm * 64 + i * 16 + lr) * 32 + lk];
      bF[i] = *(const bf16x8*)&lsB[(wn * 64 + i * 16 + lr) * 32 + lk];
    }
#pragma unroll
    for (int i = 0; i < 4; i++)
#pragma unroll
      for (int j = 0; j < 4; j++)
        acc[i][j] = __builtin_amdgcn_mfma_f32_16x16x32_bf16(aF[i], bF[j],
                                                            acc[i][j], 0, 0, 0);
    __syncthreads();
  }
  // epilogue: C/D layout col=lane&15, row=(lane>>4)*4+reg  [m89-verified]
#pragma unroll
  for (int i = 0; i < 4; i++) {
    const int row0 = tileM + wm * 64 + i * 16 + ((lane >> 4) << 2);
#pragma unroll
    for (int j = 0; j < 4; j++) {
      const int col = tileN + wn * 64 + j * 16 + lr;
      const float bv = HASBIAS ? bias[col] : 0.0f;
      f32x4 v = acc[i][j];
#pragma unroll
      for (int r = 0; r < 4; r++) {
        float x = v[r] + bv;
        if (RELU) x = fmaxf(x, 0.0f);
        if (RES)
          x += bf2f(Res[(size_t)z * sRz + (size_t)(row0 + r) * ldr + col]);
        if (OUT_BF16)
          ((unsigned short*)C)[(size_t)z * sCz + (size_t)(row0 + r) * ldc + col] =
              f2bf(x);
        else
          ((float*)C)[(size_t)z * sCz + (size_t)(row0 + r) * ldc + col] = x;
      }
    }
  }
}

// ---------------- softmax (in-place f32 row -> bf16 probs) ----------------
__launch_bounds__(256)
__global__ void softmax_kernel(float* __restrict__ e,
                               const float* __restrict__ mask, int b0) {
  const int ri = blockIdx.x;
  const int lb = blockIdx.y;
  const int b = b0 + lb;
  float* row = e + ((size_t)lb * NS + ri) * NS;
  const int t = threadIdx.x;
  float4 v = ((const float4*)row)[t];
  float4 m = ((const float4*)(mask + (size_t)b * NS))[t];
  v.x -= 1e10f * (1.0f - m.x);
  v.y -= 1e10f * (1.0f - m.y);
  v.z -= 1e10f * (1.0f - m.z);
  v.w -= 1e10f * (1.0f - m.w);
  float mx = fmaxf(fmaxf(v.x, v.y), fmaxf(v.z, v.w));
  __shared__ float red[4];
  for (int off = 32; off > 0; off >>= 1) mx = fmaxf(mx, __shfl_xor(mx, off, 64));
  if ((t & 63) == 0) red[t >> 6] = mx;
  __syncthreads();
  mx = fmaxf(fmaxf(red[0], red[1]), fmaxf(red[2], red[3]));
  const float e0 = __expf(v.x - mx), e1 = __expf(v.y - mx);
  const float e2 = __expf(v.z - mx), e3 = __expf(v.w - mx);
  float sm = e0 + e1 + e2 + e3;
  __syncthreads();  // everyone done reading red[] for max
  for (int off = 32; off > 0; off >>= 1) sm += __shfl_xor(sm, off, 64);
  if ((t & 63) == 0) red[t >> 6] = sm;
  __syncthreads();
  sm = red[0] + red[1] + red[2] + red[3];
  const float inv = 1.0f / sm;
  ushort4 o;
  o.x = f2bf(e0 * inv);
  o.y = f2bf(e1 * inv);
  o.z = f2bf(e2 * inv);
  o.w = f2bf(e3 * inv);
  ((ushort4*)row)[t] = o;  // all reads happened before barriers above
}

// ---------------- V transpose: v[b][s][h] -> vT[b][h][s] ----------------
__launch_bounds__(256)
__global__ void transpose_v(const unsigned short* __restrict__ qkv,
                            unsigned short* __restrict__ vT) {
  const int b = blockIdx.z;
  const int s0 = blockIdx.x * 64;
  const int h0 = blockIdx.y * 64;
  __shared__ unsigned short tile[64][72];
  const int t = threadIdx.x;
  const int tx = t & 7, ty = t >> 3;  // tx 0..7, ty 0..31
  const unsigned short* src = qkv + ((size_t)(b * NS + s0)) * NQKV + NH2 + h0;
#pragma unroll
  for (int i = 0; i < 2; i++) {
    const int s = ty + 32 * i;
    u16x8 vv = *(const u16x8*)(src + (size_t)s * NQKV + tx * 8);
#pragma unroll
    for (int j = 0; j < 8; j++) tile[s][tx * 8 + j] = vv[j];
  }
  __syncthreads();
  unsigned short* dst = vT + ((size_t)b * NH + h0) * NS + s0;
#pragma unroll
  for (int i = 0; i < 2; i++) {
    const int hh = ty + 32 * i;
    u16x8 o;
#pragma unroll
    for (int j = 0; j < 8; j++) o[j] = tile[tx * 8 + j][hh];
    *(u16x8*)(dst + (size_t)hh * NS + tx * 8) = o;
  }
}

// ---------------- head projection ----------------
__launch_bounds__(64)
__global__ void pred_kernel(const float* __restrict__ hidden,
                            const float* __restrict__ wobj,
                            const float* __restrict__ bobj,
                            float* __restrict__ pred) {
  const int row = blockIdx.x;
  const int lane = threadIdx.x;
  const float4* hr = (const float4*)(hidden + (size_t)row * NH);
  const float4* wr = (const float4*)wobj;
  float s = 0.f;
#pragma unroll
  for (int i = 0; i < 3; i++) {
    float4 a = hr[lane + 64 * i];
    float4 w = wr[lane + 64 * i];
    s += a.x * w.x + a.y * w.y + a.z * w.z + a.w * w.w;
  }
  for (int off = 32; off > 0; off >>= 1) s += __shfl_xor(s, off, 64);
  if (lane == 0) pred[row] = s + bobj[0];
}

// ---------------- launcher ----------------
extern "C" void kernel_launch(void* const* d_in, const int* in_sizes, int n_in,
                              void* d_out, int out_size, void* d_ws,
                              size_t ws_size, hipStream_t stream) {
  const int* relation   = (const int*)d_in[0];
  const float* lhs      = (const float*)d_in[1];
  const int* sub_head   = (const int*)d_in[2];
  const int* sub_tail   = (const int*)d_in[3];
  const float* att_mask = (const float*)d_in[4];
  const float* rel_emb  = (const float*)d_in[5];
  const float* W_rf     = (const float*)d_in[6];
  const float* b_rf     = (const float*)d_in[7];
  const float* gamma    = (const float*)d_in[8];
  const float* beta     = (const float*)d_in[9];
  const float* W_wd     = (const float*)d_in[10];
  const float* W_bd     = (const float*)d_in[11];
  const float* Wq       = (const float*)d_in[12];
  const float* bq       = (const float*)d_in[13];
  const float* Wk       = (const float*)d_in[14];
  const float* bk       = (const float*)d_in[15];
  const float* Wv       = (const float*)d_in[16];
  const float* bv       = (const float*)d_in[17];
  const float* W_obj    = (const float*)d_in[18];
  const float* b_obj    = (const float*)d_in[19];

  char* ws = (char*)d_ws;
  // offsets (all 256B aligned)
  unsigned short* Wcat = (unsigned short*)(ws + 0);          //  3,538,944
  float* bcat = (float*)(ws + 3538944);                      //      9,216
  float* wt   = (float*)(ws + 3548160);                      //     98,304
  float* bs   = (float*)(ws + 3646464);                      //     98,304
  unsigned short* xbf = (unsigned short*)(ws + 3744768);     // 50,331,648
  unsigned short* qkv = (unsigned short*)(ws + 54076416);    // 150,994,944
  unsigned short* vT  = (unsigned short*)(ws + 205071360);   // 50,331,648
  float* ebuf = (float*)(ws + 255403008);                    // CB*4,194,304

  float* out_pred = (float*)d_out;
  float* out_hidden = out_pred + NBS;

  const size_t fixed = 255403008ull;
  size_t avail = ws_size > fixed ? ws_size - fixed : 0;
  int CB = 32;
  while (CB > 1 && (size_t)CB * (size_t)NS * NS * 4 > avail) CB >>= 1;

  prep_w<<<dim3(NQKV), dim3(256), 0, stream>>>(Wq, bq, Wk, bk, Wv, bv, Wcat, bcat);
  cond_kernel<<<dim3(NB), dim3(256), 0, stream>>>(relation, lhs, sub_head,
                                                  sub_tail, rel_emb, W_rf, b_rf,
                                                  gamma, beta, W_wd, W_bd, wt, bs);
  ln_kernel<<<dim3(NBS), dim3(64), 0, stream>>>(lhs, wt, bs, xbf);

  // QKV: [32768,768] @ Wcat[2304,768]^T -> relu(+bias) -> bf16 qkv [32768,2304]
  gemm_bt<1, 1, 1, 0><<<dim3(NQKV / 128, NBS / 128, 1), dim3(256), 0, stream>>>(
      xbf, 0, NH, Wcat, 0, NH, qkv, 0, NQKV, bcat, nullptr, 0, 0, NH);

  transpose_v<<<dim3(NS / 64, NH / 64, NB), dim3(256), 0, stream>>>(qkv, vT);

  for (int b0 = 0; b0 < NB; b0 += CB) {
    // scores: e = q @ k^T  (f32)
    gemm_bt<0, 0, 0, 0><<<dim3(NS / 128, NS / 128, CB), dim3(256), 0, stream>>>(
        qkv + (size_t)b0 * NS * NQKV, (long long)NS * NQKV, NQKV,
        qkv + (size_t)b0 * NS * NQKV + NH, (long long)NS * NQKV, NQKV,
        ebuf, (long long)NS * NS, NS, nullptr, nullptr, 0, 0, NH);
    // softmax rows in place -> bf16 probs (row stride stays 2048 bf16)
    softmax_kernel<<<dim3(NS, CB), dim3(256), 0, stream>>>(ebuf, att_mask, b0);
    // hidden = probs @ v + x   (vT is [H][S] so B^T pattern holds)
    gemm_bt<0, 0, 0, 1><<<dim3(NH / 128, NS / 128, CB), dim3(256), 0, stream>>>(
        (const unsigned short*)ebuf, (long long)NS * 2048, 2048,
        vT + (size_t)b0 * NH * NS, (long long)NH * NS, NS,
        out_hidden + (size_t)b0 * NS * NH, (long long)NS * NH, NH, nullptr,
        xbf + (size_t)b0 * NS * NH, (long long)NS * NH, NH, NS);
  }

  pred_kernel<<<dim3(NBS), dim3(64), 0, stream>>>(out_hidden, W_obj, b_obj,
                                                  out_pred);
}

// Round 2
// 578.279 us; speedup vs baseline: 1.5516x; 1.5516x over previous
//
#include <hip/hip_runtime.h>

// ---------------- problem constants ----------------
constexpr int NB  = 32;     // batch
constexpr int NS  = 1024;   // seq
constexpr int NH  = 768;    // hidden
constexpr int NH2 = 1536;   // 2*hidden
constexpr int NQKV = 2304;  // 3*hidden
constexpr int NBS = NB * NS;

typedef __bf16 bf16x8 __attribute__((ext_vector_type(8)));
typedef float  f32x4  __attribute__((ext_vector_type(4)));
typedef unsigned short u16x8 __attribute__((ext_vector_type(8)));

__device__ __forceinline__ unsigned short f2bf(float f) {
  unsigned int u = __builtin_bit_cast(unsigned int, f);
  u += 0x7FFFu + ((u >> 16) & 1u);
  return (unsigned short)(u >> 16);
}
__device__ __forceinline__ float bf2f(unsigned short h) {
  return __builtin_bit_cast(float, ((unsigned int)h) << 16);
}

#define GLDS16(g, l)                                                         \
  __builtin_amdgcn_global_load_lds(                                          \
      (__attribute__((address_space(1))) void*)(g),                          \
      (__attribute__((address_space(3))) void*)(l), 16, 0, 0)

// ---------------- cond stage 0: gather + transpose ----------------
// reT[k][b] = rel_emb[relation[b]][k];  condT[768+k][b] = 0.5*(h[b,sh,k]+h[b,st,k])
__launch_bounds__(256)
__global__ void cond_pre(const int* __restrict__ relation,
                         const float* __restrict__ h,
                         const int* __restrict__ subh,
                         const int* __restrict__ subt,
                         const float* __restrict__ rel_emb,
                         float* __restrict__ reT, float* __restrict__ condT) {
  const int b = blockIdx.x, t = threadIdx.x;
  const int r = relation[b], sh = subh[b], st = subt[b];
  for (int k = t; k < NH; k += 256) {
    reT[(size_t)k * NB + b] = rel_emb[(size_t)r * NH + k];
    condT[(size_t)(NH + k) * NB + b] =
        0.5f * (h[((size_t)b * NS + sh) * NH + k] +
                h[((size_t)b * NS + st) * NH + k]);
  }
}

// ---------------- cond stage 1: rel_feature = relu6(re @ W_rf^T + b_rf) ----
// grid NH/8 blocks; block 256 = 8 j x 32 b. W row broadcast, reT coalesced.
__launch_bounds__(256)
__global__ void cond_rf(const float* __restrict__ W_rf,
                        const float* __restrict__ b_rf,
                        const float* __restrict__ reT,
                        float* __restrict__ condT) {
  const int t = threadIdx.x;
  const int b = t & 31, jl = t >> 5;
  const int j = blockIdx.x * 8 + jl;
  const float4* w4 = (const float4*)(W_rf + (size_t)j * NH);
  const float* rT = reT + b;
  float a0 = 0.f, a1 = 0.f;
  for (int k4 = 0; k4 < NH / 4; k4++) {
    float4 w = w4[k4];
    const float* c = rT + (size_t)(k4 * 4) * NB;
    a0 += w.x * c[0] + w.y * c[NB];
    a1 += w.z * c[2 * NB] + w.w * c[3 * NB];
  }
  float acc = a0 + a1 + b_rf[j];
  condT[(size_t)j * NB + b] = fminf(fmaxf(acc, 0.0f), 6.0f);
}

// ---------------- cond stage 2: wt/bs = cond @ W_{wd,bd}^T + gamma/beta ----
// grid NH/4 blocks; block 256 = 4 j x 32 b x 2 k-slices, LDS pair-reduce.
__launch_bounds__(256)
__global__ void cond_wb(const float* __restrict__ W_wd,
                        const float* __restrict__ W_bd,
                        const float* __restrict__ gamma,
                        const float* __restrict__ beta,
                        const float* __restrict__ condT,
                        float* __restrict__ wt, float* __restrict__ bs) {
  __shared__ float redW[128], redB[128];
  const int t = threadIdx.x;
  const int b = t & 31, jl = (t >> 5) & 3, ks = t >> 7;
  const int j = blockIdx.x * 4 + jl;
  const float4* ww = (const float4*)(W_wd + (size_t)j * NH2 + ks * NH);
  const float4* wb = (const float4*)(W_bd + (size_t)j * NH2 + ks * NH);
  const float* cT = condT + (size_t)ks * NH * NB + b;
  float aw0 = 0.f, aw1 = 0.f, ab0 = 0.f, ab1 = 0.f;
  for (int k4 = 0; k4 < NH / 4; k4++) {
    float4 w = ww[k4];
    float4 v = wb[k4];
    const float* c = cT + (size_t)(k4 * 4) * NB;
    float c0 = c[0], c1 = c[NB], c2 = c[2 * NB], c3 = c[3 * NB];
    aw0 += w.x * c0 + w.y * c1;
    aw1 += w.z * c2 + w.w * c3;
    ab0 += v.x * c0 + v.y * c1;
    ab1 += v.z * c2 + v.w * c3;
  }
  float aw = aw0 + aw1, ab = ab0 + ab1;
  if (ks == 1) {
    redW[t - 128] = aw;
    redB[t - 128] = ab;
  }
  __syncthreads();
  if (ks == 0) {
    aw += redW[t];
    ab += redB[t];
    wt[(size_t)b * NH + j] = aw + gamma[j];
    bs[(size_t)b * NH + j] = ab + beta[j];
  }
}

// ---------------- conditional layernorm -> x (bf16) ----------------
__launch_bounds__(64)
__global__ void ln_kernel(const float* __restrict__ h,
                          const float* __restrict__ wt,
                          const float* __restrict__ bs,
                          unsigned short* __restrict__ xbf) {
  const int row = blockIdx.x;      // 0..NBS-1
  const int b = row >> 10;
  const int lane = threadIdx.x;    // 0..63
  const float4* hr = (const float4*)(h + (size_t)row * NH);
  float4 v0 = hr[lane], v1 = hr[lane + 64], v2 = hr[lane + 128];
  float sum = 0.f, sq = 0.f;
  {
    sum += v0.x + v0.y + v0.z + v0.w;
    sq  += v0.x * v0.x + v0.y * v0.y + v0.z * v0.z + v0.w * v0.w;
    sum += v1.x + v1.y + v1.z + v1.w;
    sq  += v1.x * v1.x + v1.y * v1.y + v1.z * v1.z + v1.w * v1.w;
    sum += v2.x + v2.y + v2.z + v2.w;
    sq  += v2.x * v2.x + v2.y * v2.y + v2.z * v2.z + v2.w * v2.w;
  }
  for (int off = 32; off > 0; off >>= 1) {
    sum += __shfl_xor(sum, off, 64);
    sq  += __shfl_xor(sq, off, 64);
  }
  const float mean = sum * (1.0f / NH);
  const float var  = sq * (1.0f / NH) - mean * mean;
  const float rstd = rsqrtf(var + 1e-12f);
  const float4* wr = (const float4*)(wt + (size_t)b * NH);
  const float4* br = (const float4*)(bs + (size_t)b * NH);
  ushort4* xr = (ushort4*)(xbf + (size_t)row * NH);
#pragma unroll
  for (int i = 0; i < 3; i++) {
    float4 v = (i == 0) ? v0 : (i == 1) ? v1 : v2;
    float4 w = wr[lane + 64 * i];
    float4 bb = br[lane + 64 * i];
    ushort4 o;
    o.x = f2bf((v.x - mean) * rstd * w.x + bb.x);
    o.y = f2bf((v.y - mean) * rstd * w.y + bb.y);
    o.z = f2bf((v.z - mean) * rstd * w.z + bb.z);
    o.w = f2bf((v.w - mean) * rstd * w.w + bb.w);
    xr[lane + 64 * i] = o;
  }
}

// ---------------- weight prep: Wq/Wk/Wv -> bf16 concat ----------------
__launch_bounds__(256)
__global__ void prep_w(const float* __restrict__ Wq, const float* __restrict__ bq,
                       const float* __restrict__ Wk, const float* __restrict__ bk,
                       const float* __restrict__ Wv, const float* __restrict__ bv,
                       unsigned short* __restrict__ Wcat, float* __restrict__ bcat) {
  const int row = blockIdx.x;  // 0..2303
  const float* Wsrc;
  const float* bsrc;
  int r;
  if (row < NH) { Wsrc = Wq; bsrc = bq; r = row; }
  else if (row < NH2) { Wsrc = Wk; bsrc = bk; r = row - NH; }
  else { Wsrc = Wv; bsrc = bv; r = row - NH2; }
  for (int j = threadIdx.x; j < NH; j += 256)
    Wcat[(size_t)row * NH + j] = f2bf(Wsrc[(size_t)r * NH + j]);
  if (threadIdx.x == 0) bcat[row] = bsrc[r];
}

// ---------------- generic B^T GEMM: C = op(A @ B^T) ----------------
// A: [M,K] bf16 stride lda; B: [N,K] bf16 stride ldb; C: [M,N]
// 128x128 tile, BK=32, 4 waves (2x2), mfma 16x16x32 bf16.
template <int OUT_BF16, int RELU, int HASBIAS, int RES>
__launch_bounds__(256)
__global__ void gemm_bt(const unsigned short* __restrict__ A, long long sAz, int lda,
                        const unsigned short* __restrict__ Bm, long long sBz, int ldb,
                        void* __restrict__ C, long long sCz, int ldc,
                        const float* __restrict__ bias,
                        const unsigned short* __restrict__ Res, long long sRz, int ldr,
                        int K) {
  __shared__ unsigned short lsA[128 * 32];
  __shared__ unsigned short lsB[128 * 32];
  const int t = threadIdx.x;
  const int z = blockIdx.z;
  const int tileN = blockIdx.x * 128;  // N fastest -> B panel L2 reuse
  const int tileM = blockIdx.y * 128;
  const unsigned short* Ab = A + (size_t)z * sAz + (size_t)tileM * lda;
  const unsigned short* Bb = Bm + (size_t)z * sBz + (size_t)tileN * ldb;

  const int lane = t & 63;
  const int w = t >> 6;
  const int wm = w >> 1, wn = w & 1;
  const int lr = lane & 15;
  const int lk = (lane >> 4) << 3;

  f32x4 acc[4][4];
#pragma unroll
  for (int i = 0; i < 4; i++)
#pragma unroll
    for (int j = 0; j < 4; j++) acc[i][j] = (f32x4)0.0f;

  const int rA0 = t >> 2, cA0 = (t & 3) << 3;
  for (int k0 = 0; k0 < K; k0 += 32) {
    GLDS16(Ab + (size_t)rA0 * lda + k0 + cA0, &lsA[t * 8]);
    GLDS16(Ab + (size_t)(rA0 + 64) * lda + k0 + cA0, &lsA[(t + 256) * 8]);
    GLDS16(Bb + (size_t)rA0 * ldb + k0 + cA0, &lsB[t * 8]);
    GLDS16(Bb + (size_t)(rA0 + 64) * ldb + k0 + cA0, &lsB[(t + 256) * 8]);
    __syncthreads();
    bf16x8 aF[4], bF[4];
#pragma unroll
    for (int i = 0; i < 4; i++) {
      aF[i] = *(const bf16x8*)&lsA[(wm * 64 + i * 16 + lr) * 32 + lk];
      bF[i] = *(const bf16x8*)&lsB[(wn * 64 + i * 16 + lr) * 32 + lk];
    }
#pragma unroll
    for (int i = 0; i < 4; i++)
#pragma unroll
      for (int j = 0; j < 4; j++)
        acc[i][j] = __builtin_amdgcn_mfma_f32_16x16x32_bf16(aF[i], bF[j],
                                                            acc[i][j], 0, 0, 0);
    __syncthreads();
  }
  // epilogue: C/D layout col=lane&15, row=(lane>>4)*4+reg  [m89-verified]
#pragma unroll
  for (int i = 0; i < 4; i++) {
    const int row0 = tileM + wm * 64 + i * 16 + ((lane >> 4) << 2);
#pragma unroll
    for (int j = 0; j < 4; j++) {
      const int col = tileN + wn * 64 + j * 16 + lr;
      const float bv = HASBIAS ? bias[col] : 0.0f;
      f32x4 v = acc[i][j];
#pragma unroll
      for (int r = 0; r < 4; r++) {
        float x = v[r] + bv;
        if (RELU) x = fmaxf(x, 0.0f);
        if (RES)
          x += bf2f(Res[(size_t)z * sRz + (size_t)(row0 + r) * ldr + col]);
        if (OUT_BF16)
          ((unsigned short*)C)[(size_t)z * sCz + (size_t)(row0 + r) * ldc + col] =
              f2bf(x);
        else
          ((float*)C)[(size_t)z * sCz + (size_t)(row0 + r) * ldc + col] = x;
      }
    }
  }
}

// ---------------- softmax (in-place f32 row -> bf16 probs) ----------------
__launch_bounds__(256)
__global__ void softmax_kernel(float* __restrict__ e,
                               const float* __restrict__ mask, int b0) {
  const int ri = blockIdx.x;
  const int lb = blockIdx.y;
  const int b = b0 + lb;
  float* row = e + ((size_t)lb * NS + ri) * NS;
  const int t = threadIdx.x;
  float4 v = ((const float4*)row)[t];
  float4 m = ((const float4*)(mask + (size_t)b * NS))[t];
  v.x -= 1e10f * (1.0f - m.x);
  v.y -= 1e10f * (1.0f - m.y);
  v.z -= 1e10f * (1.0f - m.z);
  v.w -= 1e10f * (1.0f - m.w);
  float mx = fmaxf(fmaxf(v.x, v.y), fmaxf(v.z, v.w));
  __shared__ float red[4];
  for (int off = 32; off > 0; off >>= 1) mx = fmaxf(mx, __shfl_xor(mx, off, 64));
  if ((t & 63) == 0) red[t >> 6] = mx;
  __syncthreads();
  mx = fmaxf(fmaxf(red[0], red[1]), fmaxf(red[2], red[3]));
  const float e0 = __expf(v.x - mx), e1 = __expf(v.y - mx);
  const float e2 = __expf(v.z - mx), e3 = __expf(v.w - mx);
  float sm = e0 + e1 + e2 + e3;
  __syncthreads();  // everyone done reading red[] for max
  for (int off = 32; off > 0; off >>= 1) sm += __shfl_xor(sm, off, 64);
  if ((t & 63) == 0) red[t >> 6] = sm;
  __syncthreads();
  sm = red[0] + red[1] + red[2] + red[3];
  const float inv = 1.0f / sm;
  ushort4 o;
  o.x = f2bf(e0 * inv);
  o.y = f2bf(e1 * inv);
  o.z = f2bf(e2 * inv);
  o.w = f2bf(e3 * inv);
  ((ushort4*)row)[t] = o;  // all reads happened before barriers above
}

// ---------------- V transpose: v[b][s][h] -> vT[b][h][s] ----------------
__launch_bounds__(256)
__global__ void transpose_v(const unsigned short* __restrict__ qkv,
                            unsigned short* __restrict__ vT) {
  const int b = blockIdx.z;
  const int s0 = blockIdx.x * 64;
  const int h0 = blockIdx.y * 64;
  __shared__ unsigned short tile[64][72];
  const int t = threadIdx.x;
  const int tx = t & 7, ty = t >> 3;  // tx 0..7, ty 0..31
  const unsigned short* src = qkv + ((size_t)(b * NS + s0)) * NQKV + NH2 + h0;
#pragma unroll
  for (int i = 0; i < 2; i++) {
    const int s = ty + 32 * i;
    u16x8 vv = *(const u16x8*)(src + (size_t)s * NQKV + tx * 8);
#pragma unroll
    for (int j = 0; j < 8; j++) tile[s][tx * 8 + j] = vv[j];
  }
  __syncthreads();
  unsigned short* dst = vT + ((size_t)b * NH + h0) * NS + s0;
#pragma unroll
  for (int i = 0; i < 2; i++) {
    const int hh = ty + 32 * i;
    u16x8 o;
#pragma unroll
    for (int j = 0; j < 8; j++) o[j] = tile[tx * 8 + j][hh];
    *(u16x8*)(dst + (size_t)hh * NS + tx * 8) = o;
  }
}

// ---------------- head projection ----------------
__launch_bounds__(64)
__global__ void pred_kernel(const float* __restrict__ hidden,
                            const float* __restrict__ wobj,
                            const float* __restrict__ bobj,
                            float* __restrict__ pred) {
  const int row = blockIdx.x;
  const int lane = threadIdx.x;
  const float4* hr = (const float4*)(hidden + (size_t)row * NH);
  const float4* wr = (const float4*)wobj;
  float s = 0.f;
#pragma unroll
  for (int i = 0; i < 3; i++) {
    float4 a = hr[lane + 64 * i];
    float4 w = wr[lane + 64 * i];
    s += a.x * w.x + a.y * w.y + a.z * w.z + a.w * w.w;
  }
  for (int off = 32; off > 0; off >>= 1) s += __shfl_xor(s, off, 64);
  if (lane == 0) pred[row] = s + bobj[0];
}

// ---------------- launcher ----------------
extern "C" void kernel_launch(void* const* d_in, const int* in_sizes, int n_in,
                              void* d_out, int out_size, void* d_ws,
                              size_t ws_size, hipStream_t stream) {
  const int* relation   = (const int*)d_in[0];
  const float* lhs      = (const float*)d_in[1];
  const int* sub_head   = (const int*)d_in[2];
  const int* sub_tail   = (const int*)d_in[3];
  const float* att_mask = (const float*)d_in[4];
  const float* rel_emb  = (const float*)d_in[5];
  const float* W_rf     = (const float*)d_in[6];
  const float* b_rf     = (const float*)d_in[7];
  const float* gamma    = (const float*)d_in[8];
  const float* beta     = (const float*)d_in[9];
  const float* W_wd     = (const float*)d_in[10];
  const float* W_bd     = (const float*)d_in[11];
  const float* Wq       = (const float*)d_in[12];
  const float* bq       = (const float*)d_in[13];
  const float* Wk       = (const float*)d_in[14];
  const float* bk       = (const float*)d_in[15];
  const float* Wv       = (const float*)d_in[16];
  const float* bv       = (const float*)d_in[17];
  const float* W_obj    = (const float*)d_in[18];
  const float* b_obj    = (const float*)d_in[19];

  char* ws = (char*)d_ws;
  // offsets (all 256B aligned)
  unsigned short* Wcat = (unsigned short*)(ws + 0);          //  3,538,944
  float* bcat  = (float*)(ws + 3538944);                     //      9,216
  float* wt    = (float*)(ws + 3548160);                     //     98,304
  float* bs    = (float*)(ws + 3646464);                     //     98,304
  float* reT   = (float*)(ws + 3744768);                     //     98,304
  float* condT = (float*)(ws + 3843072);                     //    196,608
  unsigned short* xbf = (unsigned short*)(ws + 4039680);     // 50,331,648
  unsigned short* qkv = (unsigned short*)(ws + 54371328);    // 150,994,944
  unsigned short* vT  = (unsigned short*)(ws + 205366272);   // 50,331,648
  float* ebuf = (float*)(ws + 255697920);                    // CB*4,194,304

  float* out_pred = (float*)d_out;
  float* out_hidden = out_pred + NBS;

  const size_t fixed = 255697920ull;
  size_t avail = ws_size > fixed ? ws_size - fixed : 0;
  int CB = 32;
  while (CB > 1 && (size_t)CB * (size_t)NS * NS * 4 > avail) CB >>= 1;

  prep_w<<<dim3(NQKV), dim3(256), 0, stream>>>(Wq, bq, Wk, bk, Wv, bv, Wcat, bcat);
  cond_pre<<<dim3(NB), dim3(256), 0, stream>>>(relation, lhs, sub_head, sub_tail,
                                               rel_emb, reT, condT);
  cond_rf<<<dim3(NH / 8), dim3(256), 0, stream>>>(W_rf, b_rf, reT, condT);
  cond_wb<<<dim3(NH / 4), dim3(256), 0, stream>>>(W_wd, W_bd, gamma, beta, condT,
                                                  wt, bs);
  ln_kernel<<<dim3(NBS), dim3(64), 0, stream>>>(lhs, wt, bs, xbf);

  // QKV: [32768,768] @ Wcat[2304,768]^T -> relu(+bias) -> bf16 qkv [32768,2304]
  gemm_bt<1, 1, 1, 0><<<dim3(NQKV / 128, NBS / 128, 1), dim3(256), 0, stream>>>(
      xbf, 0, NH, Wcat, 0, NH, qkv, 0, NQKV, bcat, nullptr, 0, 0, NH);

  transpose_v<<<dim3(NS / 64, NH / 64, NB), dim3(256), 0, stream>>>(qkv, vT);

  for (int b0 = 0; b0 < NB; b0 += CB) {
    // scores: e = q @ k^T  (f32)
    gemm_bt<0, 0, 0, 0><<<dim3(NS / 128, NS / 128, CB), dim3(256), 0, stream>>>(
        qkv + (size_t)b0 * NS * NQKV, (long long)NS * NQKV, NQKV,
        qkv + (size_t)b0 * NS * NQKV + NH, (long long)NS * NQKV, NQKV,
        ebuf, (long long)NS * NS, NS, nullptr, nullptr, 0, 0, NH);
    // softmax rows in place -> bf16 probs (row stride stays 2048 bf16)
    softmax_kernel<<<dim3(NS, CB), dim3(256), 0, stream>>>(ebuf, att_mask, b0);
    // hidden = probs @ v + x   (vT is [H][S] so B^T pattern holds)
    gemm_bt<0, 0, 0, 1><<<dim3(NH / 128, NS / 128, CB), dim3(256), 0, stream>>>(
        (const unsigned short*)ebuf, (long long)NS * 2048, 2048,
        vT + (size_t)b0 * NH * NS, (long long)NH * NS, NS,
        out_hidden + (size_t)b0 * NS * NH, (long long)NS * NH, NH, nullptr,
        xbf + (size_t)b0 * NS * NH, (long long)NS * NH, NH, NS);
  }

  pred_kernel<<<dim3(NBS), dim3(64), 0, stream>>>(out_hidden, W_obj, b_obj,
                                                  out_pred);
}

// Round 3
// 515.338 us; speedup vs baseline: 1.7411x; 1.1221x over previous
//
#include <hip/hip_runtime.h>

// ---------------- problem constants ----------------
constexpr int NB  = 32;     // batch
constexpr int NS  = 1024;   // seq
constexpr int NH  = 768;    // hidden
constexpr int NH2 = 1536;   // 2*hidden
constexpr int NQKV = 2304;  // 3*hidden
constexpr int NBS = NB * NS;

typedef __bf16 bf16x8 __attribute__((ext_vector_type(8)));
typedef float  f32x4  __attribute__((ext_vector_type(4)));
typedef unsigned short u16x8 __attribute__((ext_vector_type(8)));

__device__ __forceinline__ unsigned short f2bf(float f) {
  unsigned int u = __builtin_bit_cast(unsigned int, f);
  u += 0x7FFFu + ((u >> 16) & 1u);
  return (unsigned short)(u >> 16);
}
__device__ __forceinline__ float bf2f(unsigned short h) {
  return __builtin_bit_cast(float, ((unsigned int)h) << 16);
}

#define GLDS16(g, l)                                                         \
  __builtin_amdgcn_global_load_lds(                                          \
      (__attribute__((address_space(1))) void*)(g),                          \
      (__attribute__((address_space(3))) void*)(l), 16, 0, 0)

#define SBAR()   asm volatile("s_barrier" ::: "memory")
#define WAITVM8() asm volatile("s_waitcnt vmcnt(8)" ::: "memory")
#define WAITVM0() asm volatile("s_waitcnt vmcnt(0)" ::: "memory")

// ---------------- cond stage 0: gather + transpose ----------------
__launch_bounds__(256)
__global__ void cond_pre(const int* __restrict__ relation,
                         const float* __restrict__ h,
                         const int* __restrict__ subh,
                         const int* __restrict__ subt,
                         const float* __restrict__ rel_emb,
                         float* __restrict__ reT, float* __restrict__ condT) {
  const int b = blockIdx.x, t = threadIdx.x;
  const int r = relation[b], sh = subh[b], st = subt[b];
  for (int k = t; k < NH; k += 256) {
    reT[(size_t)k * NB + b] = rel_emb[(size_t)r * NH + k];
    condT[(size_t)(NH + k) * NB + b] =
        0.5f * (h[((size_t)b * NS + sh) * NH + k] +
                h[((size_t)b * NS + st) * NH + k]);
  }
}

// ---------------- cond stage 1: rel_feature = relu6(re @ W_rf^T + b_rf) ----
__launch_bounds__(256)
__global__ void cond_rf(const float* __restrict__ W_rf,
                        const float* __restrict__ b_rf,
                        const float* __restrict__ reT,
                        float* __restrict__ condT) {
  const int t = threadIdx.x;
  const int b = t & 31, jl = t >> 5;
  const int j = blockIdx.x * 8 + jl;
  const float4* w4 = (const float4*)(W_rf + (size_t)j * NH);
  const float* rT = reT + b;
  float a0 = 0.f, a1 = 0.f;
  for (int k4 = 0; k4 < NH / 4; k4++) {
    float4 w = w4[k4];
    const float* c = rT + (size_t)(k4 * 4) * NB;
    a0 += w.x * c[0] + w.y * c[NB];
    a1 += w.z * c[2 * NB] + w.w * c[3 * NB];
  }
  float acc = a0 + a1 + b_rf[j];
  condT[(size_t)j * NB + b] = fminf(fmaxf(acc, 0.0f), 6.0f);
}

// ---------------- cond stage 2: wt/bs = cond @ W_{wd,bd}^T + gamma/beta ----
__launch_bounds__(256)
__global__ void cond_wb(const float* __restrict__ W_wd,
                        const float* __restrict__ W_bd,
                        const float* __restrict__ gamma,
                        const float* __restrict__ beta,
                        const float* __restrict__ condT,
                        float* __restrict__ wt, float* __restrict__ bs) {
  __shared__ float redW[128], redB[128];
  const int t = threadIdx.x;
  const int b = t & 31, jl = (t >> 5) & 3, ks = t >> 7;
  const int j = blockIdx.x * 4 + jl;
  const float4* ww = (const float4*)(W_wd + (size_t)j * NH2 + ks * NH);
  const float4* wb = (const float4*)(W_bd + (size_t)j * NH2 + ks * NH);
  const float* cT = condT + (size_t)ks * NH * NB + b;
  float aw0 = 0.f, aw1 = 0.f, ab0 = 0.f, ab1 = 0.f;
  for (int k4 = 0; k4 < NH / 4; k4++) {
    float4 w = ww[k4];
    float4 v = wb[k4];
    const float* c = cT + (size_t)(k4 * 4) * NB;
    float c0 = c[0], c1 = c[NB], c2 = c[2 * NB], c3 = c[3 * NB];
    aw0 += w.x * c0 + w.y * c1;
    aw1 += w.z * c2 + w.w * c3;
    ab0 += v.x * c0 + v.y * c1;
    ab1 += v.z * c2 + v.w * c3;
  }
  float aw = aw0 + aw1, ab = ab0 + ab1;
  if (ks == 1) {
    redW[t - 128] = aw;
    redB[t - 128] = ab;
  }
  __syncthreads();
  if (ks == 0) {
    aw += redW[t];
    ab += redB[t];
    wt[(size_t)b * NH + j] = aw + gamma[j];
    bs[(size_t)b * NH + j] = ab + beta[j];
  }
}

// ---------------- conditional layernorm -> x (bf16) ----------------
__launch_bounds__(64)
__global__ void ln_kernel(const float* __restrict__ h,
                          const float* __restrict__ wt,
                          const float* __restrict__ bs,
                          unsigned short* __restrict__ xbf) {
  const int row = blockIdx.x;      // 0..NBS-1
  const int b = row >> 10;
  const int lane = threadIdx.x;    // 0..63
  const float4* hr = (const float4*)(h + (size_t)row * NH);
  float4 v0 = hr[lane], v1 = hr[lane + 64], v2 = hr[lane + 128];
  float sum = 0.f, sq = 0.f;
  {
    sum += v0.x + v0.y + v0.z + v0.w;
    sq  += v0.x * v0.x + v0.y * v0.y + v0.z * v0.z + v0.w * v0.w;
    sum += v1.x + v1.y + v1.z + v1.w;
    sq  += v1.x * v1.x + v1.y * v1.y + v1.z * v1.z + v1.w * v1.w;
    sum += v2.x + v2.y + v2.z + v2.w;
    sq  += v2.x * v2.x + v2.y * v2.y + v2.z * v2.z + v2.w * v2.w;
  }
  for (int off = 32; off > 0; off >>= 1) {
    sum += __shfl_xor(sum, off, 64);
    sq  += __shfl_xor(sq, off, 64);
  }
  const float mean = sum * (1.0f / NH);
  const float var  = sq * (1.0f / NH) - mean * mean;
  const float rstd = rsqrtf(var + 1e-12f);
  const float4* wr = (const float4*)(wt + (size_t)b * NH);
  const float4* br = (const float4*)(bs + (size_t)b * NH);
  ushort4* xr = (ushort4*)(xbf + (size_t)row * NH);
#pragma unroll
  for (int i = 0; i < 3; i++) {
    float4 v = (i == 0) ? v0 : (i == 1) ? v1 : v2;
    float4 w = wr[lane + 64 * i];
    float4 bb = br[lane + 64 * i];
    ushort4 o;
    o.x = f2bf((v.x - mean) * rstd * w.x + bb.x);
    o.y = f2bf((v.y - mean) * rstd * w.y + bb.y);
    o.z = f2bf((v.z - mean) * rstd * w.z + bb.z);
    o.w = f2bf((v.w - mean) * rstd * w.w + bb.w);
    xr[lane + 64 * i] = o;
  }
}

// ---------------- weight prep: Wq/Wk/Wv -> bf16 concat ----------------
__launch_bounds__(256)
__global__ void prep_w(const float* __restrict__ Wq, const float* __restrict__ bq,
                       const float* __restrict__ Wk, const float* __restrict__ bk,
                       const float* __restrict__ Wv, const float* __restrict__ bv,
                       unsigned short* __restrict__ Wcat, float* __restrict__ bcat) {
  const int row = blockIdx.x;  // 0..2303
  const float* Wsrc;
  const float* bsrc;
  int r;
  if (row < NH) { Wsrc = Wq; bsrc = bq; r = row; }
  else if (row < NH2) { Wsrc = Wk; bsrc = bk; r = row - NH; }
  else { Wsrc = Wv; bsrc = bv; r = row - NH2; }
  for (int j = threadIdx.x; j < NH; j += 256)
    Wcat[(size_t)row * NH + j] = f2bf(Wsrc[(size_t)r * NH + j]);
  if (threadIdx.x == 0) bcat[row] = bsrc[r];
}

// ================= 256x256 BK=64 8-wave GEMM: C = op(A @ B^T) =============
// A: [M,K] bf16 stride lda; B: [N,K] bf16 stride ldb; C: [M,N]
// 8 waves (2M x 4N), per-wave 128x64 output, mfma 16x16x32 bf16.
// LDS 128 KiB: A/B x dbuf x [2 halves x 128 rows x 128 B], XOR-swizzled
// (c ^= (r&7)<<4, applied via pre-swizzled GLOBAL source + swizzled read).
// Schedule: prefetch distance 2 K-tiles, counted vmcnt(8) (never 0 in
// steady state), raw s_barrier (2 per K-tile), setprio around MFMA.
template <int OUT_BF16, int RELU, int HASBIAS, int RES>
__launch_bounds__(512, 2)
__global__ void gemm256(const unsigned short* __restrict__ A, long long sAz, int lda,
                        const unsigned short* __restrict__ Bm, long long sBz, int ldb,
                        void* __restrict__ C, long long sCz, int ldc,
                        const float* __restrict__ bias,
                        const unsigned short* __restrict__ Res, long long sRz, int ldr,
                        int K, int doswz) {
  extern __shared__ char lds[];   // [A: 2x32KB][B: 2x32KB]
  const int t = threadIdx.x;
  const int z = blockIdx.z;
  int id = blockIdx.x + blockIdx.y * gridDim.x;
  if (doswz) {  // XCD-aware swizzle (requires nwg % 8 == 0)
    const int cpx = (gridDim.x * gridDim.y) >> 3;
    id = (id & 7) * cpx + (id >> 3);
  }
  const int tileN = (id % gridDim.x) * 256;
  const int tileM = (id / gridDim.x) * 256;
  const unsigned short* Ab = A + (size_t)z * sAz + (size_t)tileM * lda;
  const unsigned short* Bb = Bm + (size_t)z * sBz + (size_t)tileN * ldb;

  const int lane = t & 63;
  const int w = t >> 6;
  const int wm = w >> 2, wn = w & 3;       // wave grid 2M x 4N
  const int lr = lane & 15, hi = lane >> 4;
  const int swz = (lane & 7) << 4;          // (row&7)<<4 == (lane&7)<<4 for our rows
  char* myA = lds + wm * 16384;             // wave's A half (within a buffer)
  char* myB = lds + 65536 + (wn >> 1) * 16384;
  const int rb0 = (wn & 1) * 64;            // B row offset within half

  // staging coords: thread t covers rows (hl*64 + t>>3), 16B chunk (t&7),
  // pre-swizzled global chunk = (t&7) ^ (row&7)
  const int sr = t >> 3;
  const int scc = (t & 7) ^ (sr & 7);

#define STAGE(Gb, ld, dst)                                                  \
  do {                                                                      \
    _Pragma("unroll") for (int hl_ = 0; hl_ < 4; hl_++) {                   \
      GLDS16((Gb) + (size_t)(hl_ * 64 + sr) * (ld) + scc * 8,               \
             (dst) + hl_ * 8192 + (size_t)t * 16);                          \
    }                                                                       \
  } while (0)

  f32x4 acc[8][4];
#pragma unroll
  for (int m = 0; m < 8; m++)
#pragma unroll
    for (int n = 0; n < 4; n++) acc[m][n] = (f32x4)0.0f;

  const int NT = K >> 6;  // K-tiles of 64 (K=768 -> 12, K=1024 -> 16)

  // prologue: stage kt=0 -> buf0, kt=1 -> buf1; wait kt0 (8 newest in flight)
  STAGE(Ab, lda, lds);
  STAGE(Bb, ldb, lds + 65536);
  STAGE(Ab + 64, lda, lds + 32768);
  STAGE(Bb + 64, ldb, lds + 65536 + 32768);
  WAITVM8();
  SBAR();

  for (int kt = 0; kt < NT; kt++) {
    const int bb = kt & 1;
    const char* Ah = myA + bb * 32768;
    const char* Bh = myB + bb * 32768;
#pragma unroll
    for (int ks = 0; ks < 2; ks++) {
      const int cb = (ks * 64 + hi * 16) ^ swz;
      bf16x8 af[8], bfr[4];
#pragma unroll
      for (int m = 0; m < 8; m++)
        af[m] = *(const bf16x8*)(Ah + (m * 16 + lr) * 128 + cb);
#pragma unroll
      for (int n = 0; n < 4; n++)
        bfr[n] = *(const bf16x8*)(Bh + (rb0 + n * 16 + lr) * 128 + cb);
      __builtin_amdgcn_s_setprio(1);
#pragma unroll
      for (int m = 0; m < 8; m++)
#pragma unroll
        for (int n = 0; n < 4; n++)
          acc[m][n] = __builtin_amdgcn_mfma_f32_16x16x32_bf16(af[m], bfr[n],
                                                              acc[m][n], 0, 0, 0);
      __builtin_amdgcn_s_setprio(0);
    }
    if (kt == NT - 1) break;
    SBAR();  // all reads of buf bb complete before restaging it
    if (kt + 2 < NT) {
      STAGE(Ab + (kt + 2) * 64, lda, lds + bb * 32768);
      STAGE(Bb + (kt + 2) * 64, ldb, lds + 65536 + bb * 32768);
      WAITVM8();  // kt+1 landed (only kt+2's 8 loads may remain in flight)
    } else {
      WAITVM0();  // tail: drain so kt+1 is landed
    }
    SBAR();  // staging visible to all waves
  }

  // epilogue: C/D layout col=lane&15, row=(lane>>4)*4+reg  [m89-verified]
  const int row0 = tileM + wm * 128;
  const int col0 = tileN + wn * 64;
#pragma unroll
  for (int m = 0; m < 8; m++) {
    const int rowb = row0 + m * 16 + hi * 4;
#pragma unroll
    for (int n = 0; n < 4; n++) {
      const int col = col0 + n * 16 + lr;
      const float bv = HASBIAS ? bias[col] : 0.0f;
      f32x4 v = acc[m][n];
#pragma unroll
      for (int r = 0; r < 4; r++) {
        float x = v[r] + bv;
        if (RELU) x = fmaxf(x, 0.0f);
        if (RES)
          x += bf2f(Res[(size_t)z * sRz + (size_t)(rowb + r) * ldr + col]);
        if (OUT_BF16)
          ((unsigned short*)C)[(size_t)z * sCz + (size_t)(rowb + r) * ldc + col] =
              f2bf(x);
        else
          ((float*)C)[(size_t)z * sCz + (size_t)(rowb + r) * ldc + col] = x;
      }
    }
  }
#undef STAGE
}

// ---------------- softmax (in-place f32 row -> bf16 probs) ----------------
__launch_bounds__(256)
__global__ void softmax_kernel(float* __restrict__ e,
                               const float* __restrict__ mask, int b0) {
  const int ri = blockIdx.x;
  const int lb = blockIdx.y;
  const int b = b0 + lb;
  float* row = e + ((size_t)lb * NS + ri) * NS;
  const int t = threadIdx.x;
  float4 v = ((const float4*)row)[t];
  float4 m = ((const float4*)(mask + (size_t)b * NS))[t];
  v.x -= 1e10f * (1.0f - m.x);
  v.y -= 1e10f * (1.0f - m.y);
  v.z -= 1e10f * (1.0f - m.z);
  v.w -= 1e10f * (1.0f - m.w);
  float mx = fmaxf(fmaxf(v.x, v.y), fmaxf(v.z, v.w));
  __shared__ float red[4];
  for (int off = 32; off > 0; off >>= 1) mx = fmaxf(mx, __shfl_xor(mx, off, 64));
  if ((t & 63) == 0) red[t >> 6] = mx;
  __syncthreads();
  mx = fmaxf(fmaxf(red[0], red[1]), fmaxf(red[2], red[3]));
  const float e0 = __expf(v.x - mx), e1 = __expf(v.y - mx);
  const float e2 = __expf(v.z - mx), e3 = __expf(v.w - mx);
  float sm = e0 + e1 + e2 + e3;
  __syncthreads();  // everyone done reading red[] for max
  for (int off = 32; off > 0; off >>= 1) sm += __shfl_xor(sm, off, 64);
  if ((t & 63) == 0) red[t >> 6] = sm;
  __syncthreads();
  sm = red[0] + red[1] + red[2] + red[3];
  const float inv = 1.0f / sm;
  ushort4 o;
  o.x = f2bf(e0 * inv);
  o.y = f2bf(e1 * inv);
  o.z = f2bf(e2 * inv);
  o.w = f2bf(e3 * inv);
  ((ushort4*)row)[t] = o;  // all reads happened before barriers above
}

// ---------------- V transpose: v[b][s][h] -> vT[b][h][s] ----------------
__launch_bounds__(256)
__global__ void transpose_v(const unsigned short* __restrict__ qkv,
                            unsigned short* __restrict__ vT) {
  const int b = blockIdx.z;
  const int s0 = blockIdx.x * 64;
  const int h0 = blockIdx.y * 64;
  __shared__ unsigned short tile[64][72];
  const int t = threadIdx.x;
  const int tx = t & 7, ty = t >> 3;  // tx 0..7, ty 0..31
  const unsigned short* src = qkv + ((size_t)(b * NS + s0)) * NQKV + NH2 + h0;
#pragma unroll
  for (int i = 0; i < 2; i++) {
    const int s = ty + 32 * i;
    u16x8 vv = *(const u16x8*)(src + (size_t)s * NQKV + tx * 8);
#pragma unroll
    for (int j = 0; j < 8; j++) tile[s][tx * 8 + j] = vv[j];
  }
  __syncthreads();
  unsigned short* dst = vT + ((size_t)b * NH + h0) * NS + s0;
#pragma unroll
  for (int i = 0; i < 2; i++) {
    const int hh = ty + 32 * i;
    u16x8 o;
#pragma unroll
    for (int j = 0; j < 8; j++) o[j] = tile[tx * 8 + j][hh];
    *(u16x8*)(dst + (size_t)hh * NS + tx * 8) = o;
  }
}

// ---------------- head projection ----------------
__launch_bounds__(64)
__global__ void pred_kernel(const float* __restrict__ hidden,
                            const float* __restrict__ wobj,
                            const float* __restrict__ bobj,
                            float* __restrict__ pred) {
  const int row = blockIdx.x;
  const int lane = threadIdx.x;
  const float4* hr = (const float4*)(hidden + (size_t)row * NH);
  const float4* wr = (const float4*)wobj;
  float s = 0.f;
#pragma unroll
  for (int i = 0; i < 3; i++) {
    float4 a = hr[lane + 64 * i];
    float4 w = wr[lane + 64 * i];
    s += a.x * w.x + a.y * w.y + a.z * w.z + a.w * w.w;
  }
  for (int off = 32; off > 0; off >>= 1) s += __shfl_xor(s, off, 64);
  if (lane == 0) pred[row] = s + bobj[0];
}

// ---------------- launcher ----------------
extern "C" void kernel_launch(void* const* d_in, const int* in_sizes, int n_in,
                              void* d_out, int out_size, void* d_ws,
                              size_t ws_size, hipStream_t stream) {
  const int* relation   = (const int*)d_in[0];
  const float* lhs      = (const float*)d_in[1];
  const int* sub_head   = (const int*)d_in[2];
  const int* sub_tail   = (const int*)d_in[3];
  const float* att_mask = (const float*)d_in[4];
  const float* rel_emb  = (const float*)d_in[5];
  const float* W_rf     = (const float*)d_in[6];
  const float* b_rf     = (const float*)d_in[7];
  const float* gamma    = (const float*)d_in[8];
  const float* beta     = (const float*)d_in[9];
  const float* W_wd     = (const float*)d_in[10];
  const float* W_bd     = (const float*)d_in[11];
  const float* Wq       = (const float*)d_in[12];
  const float* bq       = (const float*)d_in[13];
  const float* Wk       = (const float*)d_in[14];
  const float* bk       = (const float*)d_in[15];
  const float* Wv       = (const float*)d_in[16];
  const float* bv       = (const float*)d_in[17];
  const float* W_obj    = (const float*)d_in[18];
  const float* b_obj    = (const float*)d_in[19];

  char* ws = (char*)d_ws;
  // offsets (all 256B aligned)
  unsigned short* Wcat = (unsigned short*)(ws + 0);          //  3,538,944
  float* bcat  = (float*)(ws + 3538944);                     //      9,216
  float* wt    = (float*)(ws + 3548160);                     //     98,304
  float* bs    = (float*)(ws + 3646464);                     //     98,304
  float* reT   = (float*)(ws + 3744768);                     //     98,304
  float* condT = (float*)(ws + 3843072);                     //    196,608
  unsigned short* xbf = (unsigned short*)(ws + 4039680);     // 50,331,648
  unsigned short* qkv = (unsigned short*)(ws + 54371328);    // 150,994,944
  unsigned short* vT  = (unsigned short*)(ws + 205366272);   // 50,331,648
  float* ebuf = (float*)(ws + 255697920);                    // CB*4,194,304

  float* out_pred = (float*)d_out;
  float* out_hidden = out_pred + NBS;

  const size_t fixed = 255697920ull;
  size_t avail = ws_size > fixed ? ws_size - fixed : 0;
  int CB = 32;
  while (CB > 1 && (size_t)CB * (size_t)NS * NS * 4 > avail) CB >>= 1;

  prep_w<<<dim3(NQKV), dim3(256), 0, stream>>>(Wq, bq, Wk, bk, Wv, bv, Wcat, bcat);
  cond_pre<<<dim3(NB), dim3(256), 0, stream>>>(relation, lhs, sub_head, sub_tail,
                                               rel_emb, reT, condT);
  cond_rf<<<dim3(NH / 8), dim3(256), 0, stream>>>(W_rf, b_rf, reT, condT);
  cond_wb<<<dim3(NH / 4), dim3(256), 0, stream>>>(W_wd, W_bd, gamma, beta, condT,
                                                  wt, bs);
  ln_kernel<<<dim3(NBS), dim3(64), 0, stream>>>(lhs, wt, bs, xbf);

  // QKV: [32768,768] @ Wcat[2304,768]^T -> relu(+bias) -> bf16 qkv [32768,2304]
  gemm256<1, 1, 1, 0><<<dim3(NQKV / 256, NBS / 256, 1), dim3(512), 131072, stream>>>(
      xbf, 0, NH, Wcat, 0, NH, qkv, 0, NQKV, bcat, nullptr, 0, 0, NH, 1);

  transpose_v<<<dim3(NS / 64, NH / 64, NB), dim3(256), 0, stream>>>(qkv, vT);

  for (int b0 = 0; b0 < NB; b0 += CB) {
    // scores: e = q @ k^T  (f32)
    gemm256<0, 0, 0, 0><<<dim3(NS / 256, NS / 256, CB), dim3(512), 131072, stream>>>(
        qkv + (size_t)b0 * NS * NQKV, (long long)NS * NQKV, NQKV,
        qkv + (size_t)b0 * NS * NQKV + NH, (long long)NS * NQKV, NQKV,
        ebuf, (long long)NS * NS, NS, nullptr, nullptr, 0, 0, NH, 0);
    // softmax rows in place -> bf16 probs (row stride stays 2048 bf16)
    softmax_kernel<<<dim3(NS, CB), dim3(256), 0, stream>>>(ebuf, att_mask, b0);
    // hidden = probs @ v + x   (vT is [H][S] so B^T pattern holds)
    gemm256<0, 0, 0, 1><<<dim3(NH / 256, NS / 256, CB), dim3(512), 131072, stream>>>(
        (const unsigned short*)ebuf, (long long)NS * 2048, 2048,
        vT + (size_t)b0 * NH * NS, (long long)NH * NS, NS,
        out_hidden + (size_t)b0 * NS * NH, (long long)NS * NH, NH, nullptr,
        xbf + (size_t)b0 * NS * NH, (long long)NS * NH, NH, NS, 0);
  }

  pred_kernel<<<dim3(NBS), dim3(64), 0, stream>>>(out_hidden, W_obj, b_obj,
                                                  out_pred);
}

// Round 4
// 503.501 us; speedup vs baseline: 1.7820x; 1.0235x over previous
//
#include <hip/hip_runtime.h>

// ---------------- problem constants ----------------
constexpr int NB  = 32;     // batch
constexpr int NS  = 1024;   // seq
constexpr int NH  = 768;    // hidden
constexpr int NH2 = 1536;   // 2*hidden
constexpr int NQKV = 2304;  // 3*hidden
constexpr int NBS = NB * NS;

typedef __bf16 bf16x8 __attribute__((ext_vector_type(8)));
typedef float  f32x4  __attribute__((ext_vector_type(4)));
typedef unsigned short u16x8 __attribute__((ext_vector_type(8)));

__device__ __forceinline__ unsigned short f2bf(float f) {
  unsigned int u = __builtin_bit_cast(unsigned int, f);
  u += 0x7FFFu + ((u >> 16) & 1u);
  return (unsigned short)(u >> 16);
}
__device__ __forceinline__ float bf2f(unsigned short h) {
  return __builtin_bit_cast(float, ((unsigned int)h) << 16);
}

#define GLDS16(g, l)                                                         \
  __builtin_amdgcn_global_load_lds(                                          \
      (__attribute__((address_space(1))) void*)(g),                          \
      (__attribute__((address_space(3))) void*)(l), 16, 0, 0)

#define SBAR()    asm volatile("s_barrier" ::: "memory")
#define WAITVM0() asm volatile("s_waitcnt vmcnt(0)" ::: "memory")
#define LGKM0()                                                              \
  do {                                                                       \
    asm volatile("s_waitcnt lgkmcnt(0)" ::: "memory");                       \
    __builtin_amdgcn_sched_barrier(0);                                       \
  } while (0)

// ---------------- cond stage 0: gather + transpose ----------------
__launch_bounds__(256)
__global__ void cond_pre(const int* __restrict__ relation,
                         const float* __restrict__ h,
                         const int* __restrict__ subh,
                         const int* __restrict__ subt,
                         const float* __restrict__ rel_emb,
                         float* __restrict__ reT, float* __restrict__ condT) {
  const int b = blockIdx.x, t = threadIdx.x;
  const int r = relation[b], sh = subh[b], st = subt[b];
  for (int k = t; k < NH; k += 256) {
    reT[(size_t)k * NB + b] = rel_emb[(size_t)r * NH + k];
    condT[(size_t)(NH + k) * NB + b] =
        0.5f * (h[((size_t)b * NS + sh) * NH + k] +
                h[((size_t)b * NS + st) * NH + k]);
  }
}

// ---------------- cond stage 1: rel_feature = relu6(re @ W_rf^T + b_rf) ----
__launch_bounds__(256)
__global__ void cond_rf(const float* __restrict__ W_rf,
                        const float* __restrict__ b_rf,
                        const float* __restrict__ reT,
                        float* __restrict__ condT) {
  const int t = threadIdx.x;
  const int b = t & 31, jl = t >> 5;
  const int j = blockIdx.x * 8 + jl;
  const float4* w4 = (const float4*)(W_rf + (size_t)j * NH);
  const float* rT = reT + b;
  float a0 = 0.f, a1 = 0.f;
  for (int k4 = 0; k4 < NH / 4; k4++) {
    float4 w = w4[k4];
    const float* c = rT + (size_t)(k4 * 4) * NB;
    a0 += w.x * c[0] + w.y * c[NB];
    a1 += w.z * c[2 * NB] + w.w * c[3 * NB];
  }
  float acc = a0 + a1 + b_rf[j];
  condT[(size_t)j * NB + b] = fminf(fmaxf(acc, 0.0f), 6.0f);
}

// ---------------- cond stage 2: wt/bs = cond @ W_{wd,bd}^T + gamma/beta ----
__launch_bounds__(256)
__global__ void cond_wb(const float* __restrict__ W_wd,
                        const float* __restrict__ W_bd,
                        const float* __restrict__ gamma,
                        const float* __restrict__ beta,
                        const float* __restrict__ condT,
                        float* __restrict__ wt, float* __restrict__ bs) {
  __shared__ float redW[128], redB[128];
  const int t = threadIdx.x;
  const int b = t & 31, jl = (t >> 5) & 3, ks = t >> 7;
  const int j = blockIdx.x * 4 + jl;
  const float4* ww = (const float4*)(W_wd + (size_t)j * NH2 + ks * NH);
  const float4* wb = (const float4*)(W_bd + (size_t)j * NH2 + ks * NH);
  const float* cT = condT + (size_t)ks * NH * NB + b;
  float aw0 = 0.f, aw1 = 0.f, ab0 = 0.f, ab1 = 0.f;
  for (int k4 = 0; k4 < NH / 4; k4++) {
    float4 w = ww[k4];
    float4 v = wb[k4];
    const float* c = cT + (size_t)(k4 * 4) * NB;
    float c0 = c[0], c1 = c[NB], c2 = c[2 * NB], c3 = c[3 * NB];
    aw0 += w.x * c0 + w.y * c1;
    aw1 += w.z * c2 + w.w * c3;
    ab0 += v.x * c0 + v.y * c1;
    ab1 += v.z * c2 + v.w * c3;
  }
  float aw = aw0 + aw1, ab = ab0 + ab1;
  if (ks == 1) {
    redW[t - 128] = aw;
    redB[t - 128] = ab;
  }
  __syncthreads();
  if (ks == 0) {
    aw += redW[t];
    ab += redB[t];
    wt[(size_t)b * NH + j] = aw + gamma[j];
    bs[(size_t)b * NH + j] = ab + beta[j];
  }
}

// ---------------- conditional layernorm -> x (bf16) ----------------
__launch_bounds__(64)
__global__ void ln_kernel(const float* __restrict__ h,
                          const float* __restrict__ wt,
                          const float* __restrict__ bs,
                          unsigned short* __restrict__ xbf) {
  const int row = blockIdx.x;      // 0..NBS-1
  const int b = row >> 10;
  const int lane = threadIdx.x;    // 0..63
  const float4* hr = (const float4*)(h + (size_t)row * NH);
  float4 v0 = hr[lane], v1 = hr[lane + 64], v2 = hr[lane + 128];
  float sum = 0.f, sq = 0.f;
  {
    sum += v0.x + v0.y + v0.z + v0.w;
    sq  += v0.x * v0.x + v0.y * v0.y + v0.z * v0.z + v0.w * v0.w;
    sum += v1.x + v1.y + v1.z + v1.w;
    sq  += v1.x * v1.x + v1.y * v1.y + v1.z * v1.z + v1.w * v1.w;
    sum += v2.x + v2.y + v2.z + v2.w;
    sq  += v2.x * v2.x + v2.y * v2.y + v2.z * v2.z + v2.w * v2.w;
  }
  for (int off = 32; off > 0; off >>= 1) {
    sum += __shfl_xor(sum, off, 64);
    sq  += __shfl_xor(sq, off, 64);
  }
  const float mean = sum * (1.0f / NH);
  const float var  = sq * (1.0f / NH) - mean * mean;
  const float rstd = rsqrtf(var + 1e-12f);
  const float4* wr = (const float4*)(wt + (size_t)b * NH);
  const float4* br = (const float4*)(bs + (size_t)b * NH);
  ushort4* xr = (ushort4*)(xbf + (size_t)row * NH);
#pragma unroll
  for (int i = 0; i < 3; i++) {
    float4 v = (i == 0) ? v0 : (i == 1) ? v1 : v2;
    float4 w = wr[lane + 64 * i];
    float4 bb = br[lane + 64 * i];
    ushort4 o;
    o.x = f2bf((v.x - mean) * rstd * w.x + bb.x);
    o.y = f2bf((v.y - mean) * rstd * w.y + bb.y);
    o.z = f2bf((v.z - mean) * rstd * w.z + bb.z);
    o.w = f2bf((v.w - mean) * rstd * w.w + bb.w);
    xr[lane + 64 * i] = o;
  }
}

// ---------------- weight prep: Wq/Wk/Wv -> bf16 concat ----------------
__launch_bounds__(256)
__global__ void prep_w(const float* __restrict__ Wq, const float* __restrict__ bq,
                       const float* __restrict__ Wk, const float* __restrict__ bk,
                       const float* __restrict__ Wv, const float* __restrict__ bv,
                       unsigned short* __restrict__ Wcat, float* __restrict__ bcat) {
  const int row = blockIdx.x;  // 0..2303
  const float* Wsrc;
  const float* bsrc;
  int r;
  if (row < NH) { Wsrc = Wq; bsrc = bq; r = row; }
  else if (row < NH2) { Wsrc = Wk; bsrc = bk; r = row - NH; }
  else { Wsrc = Wv; bsrc = bv; r = row - NH2; }
  for (int j = threadIdx.x; j < NH; j += 256)
    Wcat[(size_t)row * NH + j] = f2bf(Wsrc[(size_t)r * NH + j]);
  if (threadIdx.x == 0) bcat[row] = bsrc[r];
}

// ================= 256x256 BK=64 8-wave GEMM: C = op(A @ B^T) =============
// A: [M,K] bf16 stride lda; B: [N,K] bf16 stride ldb; C: [M,N]
// 8 waves (2M x 4N), per-wave 128x64 output, mfma 16x16x32 bf16.
// LDS 128 KiB: A/B x dbuf x [256 rows x 128 B], XOR-swizzled
// (c ^= (r&7)<<4 via pre-swizzled GLOBAL source + swizzled read).
// K-loop: 4 C-quadrant phases per K-tile, each
//   {ds_read frags; (stage 4 loads, phases 0-1); s_barrier; lgkmcnt(0);
//    setprio(1); 16 MFMA; setprio(0); s_barrier}
// Prefetch distance 1 K-tile into buf^1 (provably race-free: issue after
// buf^1's reads ended at a barrier; lands into a buffer not read this tile).
// Single vmcnt(0) per K-tile at the boundary (loads had ~3 phases to land).
template <int OUT_BF16, int RELU, int HASBIAS, int RES>
__launch_bounds__(512, 2)
__global__ void gemm256(const unsigned short* __restrict__ A, long long sAz, int lda,
                        const unsigned short* __restrict__ Bm, long long sBz, int ldb,
                        void* __restrict__ C, long long sCz, int ldc,
                        const float* __restrict__ bias,
                        const unsigned short* __restrict__ Res, long long sRz, int ldr,
                        int K, int doswz) {
  extern __shared__ char lds[];   // [A: 2x32KB][B: 2x32KB]
  const int t = threadIdx.x;
  const int z = blockIdx.z;
  int id = blockIdx.x + blockIdx.y * gridDim.x;
  if (doswz) {  // XCD-aware swizzle (requires nwg % 8 == 0)
    const int cpx = (gridDim.x * gridDim.y) >> 3;
    id = (id & 7) * cpx + (id >> 3);
  }
  const int tileN = (id % gridDim.x) * 256;
  const int tileM = (id / gridDim.x) * 256;
  const unsigned short* Ab = A + (size_t)z * sAz + (size_t)tileM * lda;
  const unsigned short* Bb = Bm + (size_t)z * sBz + (size_t)tileN * ldb;

  const int lane = t & 63;
  const int w = t >> 6;
  const int wm = w >> 2, wn = w & 3;       // wave grid 2M x 4N
  const int lr = lane & 15, hi = lane >> 4;
  const int swz = (lane & 7) << 4;          // (row&7)<<4 for our frag rows
  const int rb0 = (wn & 1) * 64;            // B row offset within half

  // staging: thread t covers rows (hl*64 + t>>3), 16B chunk (t&7),
  // pre-swizzled global chunk = (t&7) ^ (row&7); LDS dest linear.
  const int sr = t >> 3;
  const int scc = (t & 7) ^ (sr & 7);

#define STAGE4(Gb, ld, dst)                                                 \
  do {                                                                      \
    _Pragma("unroll") for (int hl_ = 0; hl_ < 4; hl_++) {                   \
      GLDS16((Gb) + (size_t)(hl_ * 64 + sr) * (ld) + scc * 8,               \
             (dst) + hl_ * 8192 + (size_t)t * 16);                          \
    }                                                                       \
  } while (0)

#define RD_A(m0)                                                            \
  do {                                                                      \
    _Pragma("unroll") for (int mm_ = 0; mm_ < 4; mm_++)                     \
      _Pragma("unroll") for (int ks_ = 0; ks_ < 2; ks_++)                   \
        aF[mm_][ks_] = *(const bf16x8*)(Ah + ((m0) * 16 + mm_ * 16 + lr) * 128 + \
                                        ((ks_ * 64 + hi * 16) ^ swz));      \
  } while (0)

#define RD_B(n0)                                                            \
  do {                                                                      \
    _Pragma("unroll") for (int nn_ = 0; nn_ < 2; nn_++)                     \
      _Pragma("unroll") for (int ks_ = 0; ks_ < 2; ks_++)                   \
        bF[nn_][ks_] = *(const bf16x8*)(Bh + (rb0 + (n0) * 16 + nn_ * 16 + lr) * 128 + \
                                        ((ks_ * 64 + hi * 16) ^ swz));      \
  } while (0)

#define MFMA_Q(m0, n0)                                                      \
  do {                                                                      \
    __builtin_amdgcn_s_setprio(1);                                          \
    _Pragma("unroll") for (int ks_ = 0; ks_ < 2; ks_++)                     \
      _Pragma("unroll") for (int mm_ = 0; mm_ < 4; mm_++)                   \
        _Pragma("unroll") for (int nn_ = 0; nn_ < 2; nn_++)                 \
          acc[(m0) + mm_][(n0) + nn_] = __builtin_amdgcn_mfma_f32_16x16x32_bf16( \
              aF[mm_][ks_], bF[nn_][ks_], acc[(m0) + mm_][(n0) + nn_], 0, 0, 0); \
    __builtin_amdgcn_s_setprio(0);                                          \
  } while (0)

  f32x4 acc[8][4];
#pragma unroll
  for (int m = 0; m < 8; m++)
#pragma unroll
    for (int n = 0; n < 4; n++) acc[m][n] = (f32x4)0.0f;

  const int NT = K >> 6;  // K-tiles of 64

  // prologue: stage kt=0 -> buf0, drain, publish
  STAGE4(Ab, lda, lds);
  STAGE4(Bb, ldb, lds + 65536);
  WAITVM0();
  SBAR();

  for (int kt = 0; kt < NT; kt++) {
    const int bb = kt & 1;
    const char* Ah = lds + bb * 32768 + wm * 16384;
    const char* Bh = lds + 65536 + bb * 32768 + (wn >> 1) * 16384;
    const int stg = (kt + 1 < NT);
    bf16x8 aF[4][2], bF[2][2];

    // phase 0: quadrant (m0-3, n0-1); stage next A
    RD_A(0);
    RD_B(0);
    if (stg) STAGE4(Ab + (size_t)(kt + 1) * 64, lda, lds + (bb ^ 1) * 32768);
    SBAR();
    LGKM0();
    MFMA_Q(0, 0);
    SBAR();

    // phase 1: quadrant (m0-3, n2-3); stage next B
    RD_B(2);
    if (stg)
      STAGE4(Bb + (size_t)(kt + 1) * 64, ldb, lds + 65536 + (bb ^ 1) * 32768);
    SBAR();
    LGKM0();
    MFMA_Q(0, 2);
    SBAR();

    // phase 2: quadrant (m4-7, n2-3)
    RD_A(4);
    SBAR();
    LGKM0();
    MFMA_Q(4, 2);
    SBAR();

    // phase 3: quadrant (m4-7, n0-1); boundary drain
    RD_B(0);
    SBAR();
    LGKM0();
    MFMA_Q(4, 0);
    if (stg) WAITVM0();
    SBAR();
  }

  // epilogue: C/D layout col=lane&15, row=(lane>>4)*4+reg  [m89-verified]
  const int row0 = tileM + wm * 128;
  const int col0 = tileN + wn * 64;
#pragma unroll
  for (int m = 0; m < 8; m++) {
    const int rowb = row0 + m * 16 + hi * 4;
#pragma unroll
    for (int n = 0; n < 4; n++) {
      const int col = col0 + n * 16 + lr;
      const float bv = HASBIAS ? bias[col] : 0.0f;
      f32x4 v = acc[m][n];
#pragma unroll
      for (int r = 0; r < 4; r++) {
        float x = v[r] + bv;
        if (RELU) x = fmaxf(x, 0.0f);
        if (RES)
          x += bf2f(Res[(size_t)z * sRz + (size_t)(rowb + r) * ldr + col]);
        if (OUT_BF16)
          ((unsigned short*)C)[(size_t)z * sCz + (size_t)(rowb + r) * ldc + col] =
              f2bf(x);
        else
          ((float*)C)[(size_t)z * sCz + (size_t)(rowb + r) * ldc + col] = x;
      }
    }
  }
#undef STAGE4
#undef RD_A
#undef RD_B
#undef MFMA_Q
}

// ---------------- softmax (in-place f32 row -> bf16 probs) ----------------
__launch_bounds__(256)
__global__ void softmax_kernel(float* __restrict__ e,
                               const float* __restrict__ mask, int b0) {
  const int ri = blockIdx.x;
  const int lb = blockIdx.y;
  const int b = b0 + lb;
  float* row = e + ((size_t)lb * NS + ri) * NS;
  const int t = threadIdx.x;
  float4 v = ((const float4*)row)[t];
  float4 m = ((const float4*)(mask + (size_t)b * NS))[t];
  v.x -= 1e10f * (1.0f - m.x);
  v.y -= 1e10f * (1.0f - m.y);
  v.z -= 1e10f * (1.0f - m.z);
  v.w -= 1e10f * (1.0f - m.w);
  float mx = fmaxf(fmaxf(v.x, v.y), fmaxf(v.z, v.w));
  __shared__ float red[4];
  for (int off = 32; off > 0; off >>= 1) mx = fmaxf(mx, __shfl_xor(mx, off, 64));
  if ((t & 63) == 0) red[t >> 6] = mx;
  __syncthreads();
  mx = fmaxf(fmaxf(red[0], red[1]), fmaxf(red[2], red[3]));
  const float e0 = __expf(v.x - mx), e1 = __expf(v.y - mx);
  const float e2 = __expf(v.z - mx), e3 = __expf(v.w - mx);
  float sm = e0 + e1 + e2 + e3;
  __syncthreads();  // everyone done reading red[] for max
  for (int off = 32; off > 0; off >>= 1) sm += __shfl_xor(sm, off, 64);
  if ((t & 63) == 0) red[t >> 6] = sm;
  __syncthreads();
  sm = red[0] + red[1] + red[2] + red[3];
  const float inv = 1.0f / sm;
  ushort4 o;
  o.x = f2bf(e0 * inv);
  o.y = f2bf(e1 * inv);
  o.z = f2bf(e2 * inv);
  o.w = f2bf(e3 * inv);
  ((ushort4*)row)[t] = o;  // all reads happened before barriers above
}

// ---------------- V transpose: v[b][s][h] -> vT[b][h][s] ----------------
__launch_bounds__(256)
__global__ void transpose_v(const unsigned short* __restrict__ qkv,
                            unsigned short* __restrict__ vT) {
  const int b = blockIdx.z;
  const int s0 = blockIdx.x * 64;
  const int h0 = blockIdx.y * 64;
  __shared__ unsigned short tile[64][72];
  const int t = threadIdx.x;
  const int tx = t & 7, ty = t >> 3;  // tx 0..7, ty 0..31
  const unsigned short* src = qkv + ((size_t)(b * NS + s0)) * NQKV + NH2 + h0;
#pragma unroll
  for (int i = 0; i < 2; i++) {
    const int s = ty + 32 * i;
    u16x8 vv = *(const u16x8*)(src + (size_t)s * NQKV + tx * 8);
#pragma unroll
    for (int j = 0; j < 8; j++) tile[s][tx * 8 + j] = vv[j];
  }
  __syncthreads();
  unsigned short* dst = vT + ((size_t)b * NH + h0) * NS + s0;
#pragma unroll
  for (int i = 0; i < 2; i++) {
    const int hh = ty + 32 * i;
    u16x8 o;
#pragma unroll
    for (int j = 0; j < 8; j++) o[j] = tile[tx * 8 + j][hh];
    *(u16x8*)(dst + (size_t)hh * NS + tx * 8) = o;
  }
}

// ---------------- head projection ----------------
__launch_bounds__(64)
__global__ void pred_kernel(const float* __restrict__ hidden,
                            const float* __restrict__ wobj,
                            const float* __restrict__ bobj,
                            float* __restrict__ pred) {
  const int row = blockIdx.x;
  const int lane = threadIdx.x;
  const float4* hr = (const float4*)(hidden + (size_t)row * NH);
  const float4* wr = (const float4*)wobj;
  float s = 0.f;
#pragma unroll
  for (int i = 0; i < 3; i++) {
    float4 a = hr[lane + 64 * i];
    float4 w = wr[lane + 64 * i];
    s += a.x * w.x + a.y * w.y + a.z * w.z + a.w * w.w;
  }
  for (int off = 32; off > 0; off >>= 1) s += __shfl_xor(s, off, 64);
  if (lane == 0) pred[row] = s + bobj[0];
}

// ---------------- launcher ----------------
extern "C" void kernel_launch(void* const* d_in, const int* in_sizes, int n_in,
                              void* d_out, int out_size, void* d_ws,
                              size_t ws_size, hipStream_t stream) {
  const int* relation   = (const int*)d_in[0];
  const float* lhs      = (const float*)d_in[1];
  const int* sub_head   = (const int*)d_in[2];
  const int* sub_tail   = (const int*)d_in[3];
  const float* att_mask = (const float*)d_in[4];
  const float* rel_emb  = (const float*)d_in[5];
  const float* W_rf     = (const float*)d_in[6];
  const float* b_rf     = (const float*)d_in[7];
  const float* gamma    = (const float*)d_in[8];
  const float* beta     = (const float*)d_in[9];
  const float* W_wd     = (const float*)d_in[10];
  const float* W_bd     = (const float*)d_in[11];
  const float* Wq       = (const float*)d_in[12];
  const float* bq       = (const float*)d_in[13];
  const float* Wk       = (const float*)d_in[14];
  const float* bk       = (const float*)d_in[15];
  const float* Wv       = (const float*)d_in[16];
  const float* bv       = (const float*)d_in[17];
  const float* W_obj    = (const float*)d_in[18];
  const float* b_obj    = (const float*)d_in[19];

  char* ws = (char*)d_ws;
  // offsets (all 256B aligned)
  unsigned short* Wcat = (unsigned short*)(ws + 0);          //  3,538,944
  float* bcat  = (float*)(ws + 3538944);                     //      9,216
  float* wt    = (float*)(ws + 3548160);                     //     98,304
  float* bs    = (float*)(ws + 3646464);                     //     98,304
  float* reT   = (float*)(ws + 3744768);                     //     98,304
  float* condT = (float*)(ws + 3843072);                     //    196,608
  unsigned short* xbf = (unsigned short*)(ws + 4039680);     // 50,331,648
  unsigned short* qkv = (unsigned short*)(ws + 54371328);    // 150,994,944
  unsigned short* vT  = (unsigned short*)(ws + 205366272);   // 50,331,648
  float* ebuf = (float*)(ws + 255697920);                    // CB*4,194,304

  float* out_pred = (float*)d_out;
  float* out_hidden = out_pred + NBS;

  const size_t fixed = 255697920ull;
  size_t avail = ws_size > fixed ? ws_size - fixed : 0;
  int CB = 32;
  while (CB > 1 && (size_t)CB * (size_t)NS * NS * 4 > avail) CB >>= 1;

  prep_w<<<dim3(NQKV), dim3(256), 0, stream>>>(Wq, bq, Wk, bk, Wv, bv, Wcat, bcat);
  cond_pre<<<dim3(NB), dim3(256), 0, stream>>>(relation, lhs, sub_head, sub_tail,
                                               rel_emb, reT, condT);
  cond_rf<<<dim3(NH / 8), dim3(256), 0, stream>>>(W_rf, b_rf, reT, condT);
  cond_wb<<<dim3(NH / 4), dim3(256), 0, stream>>>(W_wd, W_bd, gamma, beta, condT,
                                                  wt, bs);
  ln_kernel<<<dim3(NBS), dim3(64), 0, stream>>>(lhs, wt, bs, xbf);

  // QKV: [32768,768] @ Wcat[2304,768]^T -> relu(+bias) -> bf16 qkv [32768,2304]
  gemm256<1, 1, 1, 0><<<dim3(NQKV / 256, NBS / 256, 1), dim3(512), 131072, stream>>>(
      xbf, 0, NH, Wcat, 0, NH, qkv, 0, NQKV, bcat, nullptr, 0, 0, NH, 1);

  transpose_v<<<dim3(NS / 64, NH / 64, NB), dim3(256), 0, stream>>>(qkv, vT);

  for (int b0 = 0; b0 < NB; b0 += CB) {
    // scores: e = q @ k^T  (f32)
    gemm256<0, 0, 0, 0><<<dim3(NS / 256, NS / 256, CB), dim3(512), 131072, stream>>>(
        qkv + (size_t)b0 * NS * NQKV, (long long)NS * NQKV, NQKV,
        qkv + (size_t)b0 * NS * NQKV + NH, (long long)NS * NQKV, NQKV,
        ebuf, (long long)NS * NS, NS, nullptr, nullptr, 0, 0, NH, 0);
    // softmax rows in place -> bf16 probs (row stride stays 2048 bf16)
    softmax_kernel<<<dim3(NS, CB), dim3(256), 0, stream>>>(ebuf, att_mask, b0);
    // hidden = probs @ v + x   (vT is [H][S] so B^T pattern holds)
    gemm256<0, 0, 0, 1><<<dim3(NH / 256, NS / 256, CB), dim3(512), 131072, stream>>>(
        (const unsigned short*)ebuf, (long long)NS * 2048, 2048,
        vT + (size_t)b0 * NH * NS, (long long)NH * NS, NS,
        out_hidden + (size_t)b0 * NS * NH, (long long)NS * NH, NH, nullptr,
        xbf + (size_t)b0 * NS * NH, (long long)NS * NH, NH, NS, 0);
  }

  pred_kernel<<<dim3(NBS), dim3(64), 0, stream>>>(out_hidden, W_obj, b_obj,
                                                  out_pred);
}